// Round 11
// baseline (4061.809 us; speedup 1.0000x reference)
//
#include <hip/hip_runtime.h>
#include <hip/hip_bf16.h>
#include <cmath>

#define HID 512
#define TSTEPS 784
#define BATCH 256
#define NCLS 10
#define NBLK 128    // 8 group-pairs x 16 col-slices
#define NGRP 16     // 16 groups (16 batch rows each)

typedef __bf16 bf16x8 __attribute__((ext_vector_type(8)));
typedef float f32x4 __attribute__((ext_vector_type(4)));
typedef float f32x2 __attribute__((ext_vector_type(2)));
typedef int   i32x4 __attribute__((ext_vector_type(4)));

#define SWS(r) (((unsigned)(r) & 7u) << 4)

// LLC-coherent ops (bypass L1+L2; proven cross-XCD-visible rounds 4/5/9)
#define LDX4_CC(dst, addr) \
    asm volatile("global_load_dwordx4 %0, %1, off sc0 sc1" : "=v"(dst) : "v"(addr) : "memory")
#define STOREDW_CC(addr, val) \
    asm volatile("global_store_dword %0, %1, off sc0 sc1" :: "v"(addr), "v"(val) : "memory")

__device__ __forceinline__ unsigned lddw_cc_wait(const unsigned* a) {
    unsigned d;
    asm volatile("global_load_dword %0, %1, off sc0 sc1\n\ts_waitcnt vmcnt(0)"
                 : "=v"(d) : "v"(a) : "memory");
    return d;
}

// zero h0+h1 (512KB bf16) + flags (4KB), transpose x -> xT[784][256]
__global__ void init_all(const float* __restrict__ x, float* __restrict__ xT,
                         uint4* __restrict__ hz, unsigned* __restrict__ flg) {
    int t = blockIdx.x, tid = threadIdx.x;
    xT[t * BATCH + tid] = x[tid * TSTEPS + t];
    int i = t * 256 + tid;
    if (i < (512 << 10) / 16) hz[i] = make_uint4(0u, 0u, 0u, 0u);
    if (i < NGRP * 64) flg[i] = 0u;
}

__device__ __forceinline__ float sigmoid_f(float v) {
    return __fdividef(1.f, 1.f + __expf(-v));
}
__device__ __forceinline__ float tanh_f(float v) {
    float e = __expf(fminf(fmaxf(2.f * v, -30.f), 30.f));
    return __fdividef(e - 1.f, e + 1.f);
}

// Persistent LSTM, two-group time-sharing.
// 128 blocks = 8 pairs x 16 col-slices(32 cols). Block serves groups 2p,2p+1
// (16 batch rows each) with ONE shared 128KB W slice in LDS. Phase A computes
// group A while group B's exchange propagates, and vice versa. Flag publish
// rides the other phase's stage drain; stage threads poll only their own
// producer's flag. h exchanged via LLC (sc0 sc1), bf16, one dword per store.
__global__ __launch_bounds__(512)
void lstm_persist(const float* __restrict__ xT,     // [784][256]
                  const float* __restrict__ W_hh,   // [2048][512] fp32
                  const float* __restrict__ w_in,   // [2048]
                  const float* __restrict__ b_ih,
                  const float* __restrict__ b_hh,
                  __bf16* __restrict__ h0,          // [256][512] bf16
                  __bf16* __restrict__ h1,
                  float* __restrict__ hf,           // [256][512] fp32
                  unsigned* __restrict__ flg)       // [NGRP*64]
{
    __shared__ __align__(16) __bf16 wlds[128 * HID];  // 128 KB, XOR-swizzled
    __shared__ __align__(16) __bf16 hlds[16 * HID];   // 16 KB, XOR-swizzled
    __shared__ float gl[4][16][33];                   // gate exchange
    __shared__ float xl2[2][16];

    const int tid  = threadIdx.x;
    const int lane = tid & 63;
    const int w    = tid >> 6;           // wave 0..7
    const int s    = w & 3;              // gate (i,f,g,o)
    const int ch   = w >> 2;             // col half (16 cols each)
    const int p    = blockIdx.x >> 4;    // pair (8)
    const int cs   = blockIdx.x & 15;    // col slice (16)
    const int b0A  = (p * 2) * 16;
    const int b0B  = (p * 2 + 1) * 16;
    const int j0   = cs * 32;
    const int rlo  = lane & 15;
    const int khi  = (lane >> 4) * 8;    // elements

    unsigned* flagsA = flg + (p * 2) * 64;
    unsigned* flagsB = flg + (p * 2 + 1) * 64;

    // ---- stage W slice (128 rows x 512) into LDS once (fp32->bf16, swizzled) ----
    {
        int r = tid >> 2;                // local row 0..127
        int q = tid & 3;
        int gs = r >> 5, jj = r & 31;
        const float* src = W_hh + (size_t)(gs * HID + j0 + jj) * HID + q * 128;
        char* wp = (char*)wlds;
        unsigned rowb = (unsigned)r * (HID * 2);
        unsigned sw   = SWS(r);
        #pragma unroll
        for (int cc = 0; cc < 128; cc += 8) {
            float4 va = *(const float4*)(src + cc);
            float4 vb = *(const float4*)(src + cc + 4);
            bf16x8 pk;
            pk[0]=(__bf16)va.x; pk[1]=(__bf16)va.y; pk[2]=(__bf16)va.z; pk[3]=(__bf16)va.w;
            pk[4]=(__bf16)vb.x; pk[5]=(__bf16)vb.y; pk[6]=(__bf16)vb.z; pk[7]=(__bf16)vb.w;
            *(bf16x8*)(wp + ((rowb + (unsigned)(q * 128 + cc) * 2) ^ sw)) = pk;
        }
    }

    // cell mapping (tid<256): row Rc=tid>>4 (0..15), cols c2,c2+1 (of 32)
    const int Rc = tid >> 4;
    const int c2 = (tid & 15) * 2;
    float win_r[4][2], bias_r[4][2];   // shared between both groups (same cols)
    #pragma unroll
    for (int g = 0; g < 4; ++g)
        #pragma unroll
        for (int ii = 0; ii < 2; ++ii) {
            int idx = g * HID + j0 + c2 + ii;
            win_r[g][ii]  = w_in[idx];
            bias_r[g][ii] = b_ih[idx] + b_hh[idx];
        }
    float cregA[2] = {0.f, 0.f}, cregB[2] = {0.f, 0.f};

    // staging mapping: row rS (0..15), segment seg (0..31) of 16 bf16 cols (32B)
    const int rS  = tid & 15;
    const int seg = tid >> 4;
    const unsigned rowbS = (unsigned)rS * (HID * 2);
    const unsigned swS   = SWS(rS);

    // B-fragment base: local W row rB = s*32 + ch*16 + rlo
    const unsigned rBb = (unsigned)(s * 32 + ch * 16 + rlo) * (HID * 2);
    const unsigned swB = SWS(rlo);
    const char* wbp = (const char*)wlds;
    const char* hbp = (const char*)hlds;
    char* hwp = (char*)hlds;

    __syncthreads();

    // one phase: poll own producer flag, stage h, publish other group's flag,
    // MFMA, cell, fire h stores. 2 barriers.
    auto phase = [&](int t, int b0, const __bf16* hprev, __bf16* hnext,
                     unsigned* fpoll, unsigned* fstore, unsigned sval,
                     float (&creg)[2], float* xlp) {
        // ---- poll + stage (per-thread producer flag) ----
        {
            const unsigned* fp = fpoll + (seg >> 1);
            while (lddw_cc_wait(fp) < (unsigned)t) __builtin_amdgcn_s_sleep(1);
            const __bf16* gsrc = hprev + (size_t)(b0 + rS) * HID + seg * 16;
            i32x4 v0, v1;
            LDX4_CC(v0, gsrc);
            LDX4_CC(v1, gsrc + 8);
            asm volatile("s_waitcnt vmcnt(0)" ::: "memory");  // also drains own
            __builtin_amdgcn_sched_barrier(0);                // prev-phase h stores
            unsigned base = rowbS + (unsigned)seg * 32u;
            *(i32x4*)(hwp + ((base +  0u) ^ swS)) = v0;
            *(i32x4*)(hwp + ((base + 16u) ^ swS)) = v1;
            if (tid < 16) xlp[tid] = xT[t * BATCH + b0 + tid];
        }
        __syncthreads();   // hlds ready + ALL threads' prev-phase stores drained
        if (tid == 0) STOREDW_CC(fstore + cs, (int)sval);   // publish other group

        // ---- gates tile: 16 rows x 16 cols for gate s, col-half ch ----
        f32x4 acc0 = {0.f,0.f,0.f,0.f};
        #pragma unroll
        for (int ks = 0; ks < 16; ++ks) {
            unsigned colb = (unsigned)(khi * 2 + ks * 64);
            bf16x8 a0 = *(const bf16x8*)(hbp + (((unsigned)rlo * 1024u + colb) ^ SWS(rlo)));
            bf16x8 b  = *(const bf16x8*)(wbp + ((rBb + colb) ^ swB));
            acc0 = __builtin_amdgcn_mfma_f32_16x16x32_bf16(a0, b, acc0, 0, 0, 0);
        }
        #pragma unroll
        for (int rr = 0; rr < 4; ++rr) {
            int rowl = (lane >> 4) * 4 + rr;   // D: col=lane&15, row=(lane>>4)*4+reg
            gl[s][rowl][ch * 16 + rlo] = acc0[rr];
        }
        __syncthreads();   // gl ready

        // ---- cell update (tid<256: 2 cols), fire-and-forget h store ----
        if (tid < 256) {
            float xv = xlp[Rc];
            float hn2[2];
            #pragma unroll
            for (int ii = 0; ii < 2; ++ii) {
                int ccx = c2 + ii;
                float gi = gl[0][Rc][ccx] + xv * win_r[0][ii] + bias_r[0][ii];
                float gf = gl[1][Rc][ccx] + xv * win_r[1][ii] + bias_r[1][ii];
                float gg = gl[2][Rc][ccx] + xv * win_r[2][ii] + bias_r[2][ii];
                float go = gl[3][Rc][ccx] + xv * win_r[3][ii] + bias_r[3][ii];
                float cn = sigmoid_f(gf) * creg[ii] + sigmoid_f(gi) * tanh_f(gg);
                creg[ii] = cn;
                hn2[ii]  = sigmoid_f(go) * tanh_f(cn);
            }
            if (t == TSTEPS - 1) {
                *(f32x2*)(hf + (size_t)(b0 + Rc) * HID + j0 + c2) = (f32x2){hn2[0], hn2[1]};
            } else {
                union { __bf16 b[2]; int i; } u;
                u.b[0] = (__bf16)hn2[0]; u.b[1] = (__bf16)hn2[1];
                __bf16* dst = hnext + (size_t)(b0 + Rc) * HID + j0 + c2;
                STOREDW_CC(dst, u.i);
            }
        }
        // no trailing barrier: next phase's stage is ordered per-thread, and
        // its hlds/gl writes are fenced by that phase's own barriers.
    };

    for (int t = 0; t < TSTEPS; ++t) {
        const __bf16* hprev = (t & 1) ? h1 : h0;
        __bf16* hnext       = (t & 1) ? h0 : h1;
        // phase A: compute group A step t; publish flagB=t (h_B(t) drained)
        phase(t, b0A, hprev, hnext, flagsA, flagsB, (unsigned)t, cregA, xl2[0]);
        // phase B: compute group B step t; publish flagA=t+1 (h_A(t+1) drained)
        phase(t, b0B, hprev, hnext, flagsB, flagsA, (unsigned)(t + 1), cregB, xl2[1]);
    }
}

// out[b][j] = h_T[b] . W_lin[j] + b_lin[j]
__global__ void head(const float* __restrict__ hfp, const float* __restrict__ Wl,
                     const float* __restrict__ bl_, float* __restrict__ out)
{
    __shared__ float hr[HID];
    int b = blockIdx.x;
    for (int k = threadIdx.x; k < HID; k += blockDim.x) hr[k] = hfp[b * HID + k];
    __syncthreads();
    int j = threadIdx.x;
    if (j < NCLS) {
        float acc = bl_[j];
        for (int k = 0; k < HID; ++k) acc += hr[k] * Wl[j * HID + k];
        out[b * NCLS + j] = acc;
    }
}

extern "C" void kernel_launch(void* const* d_in, const int* in_sizes, int n_in,
                              void* d_out, int out_size, void* d_ws, size_t ws_size,
                              hipStream_t stream) {
    const float* inputs = (const float*)d_in[0];
    const float* W_ih   = (const float*)d_in[1];
    const float* W_hh   = (const float*)d_in[2];
    const float* b_ih   = (const float*)d_in[3];
    const float* b_hh   = (const float*)d_in[4];
    const float* W_lin  = (const float*)d_in[5];
    const float* b_lin  = (const float*)d_in[6];

    // ws: h0 256K | h1 256K | hf 512K | xT 784K | flags 4K
    const size_t OFS_H1  = 256u << 10;
    const size_t OFS_HF  = 512u << 10;
    const size_t OFS_XT  = 1024u << 10;
    const size_t OFS_FLG = OFS_XT + (size_t)TSTEPS * BATCH * 4;   // 128B-aligned
    const size_t NEEDED  = OFS_FLG + NGRP * 64 * 4;
    if (ws_size < NEEDED) return;

    char* ws = (char*)d_ws;
    __bf16* h0 = (__bf16*)ws;
    __bf16* h1 = (__bf16*)(ws + OFS_H1);
    float*  hf = (float*)(ws + OFS_HF);
    float*  xT = (float*)(ws + OFS_XT);
    unsigned* flg = (unsigned*)(ws + OFS_FLG);

    init_all<<<TSTEPS, BATCH, 0, stream>>>(inputs, xT, (uint4*)h0, flg);

    lstm_persist<<<NBLK, 512, 0, stream>>>(xT, W_hh, W_ih, b_ih, b_hh,
                                           h0, h1, hf, flg);

    head<<<BATCH, 64, 0, stream>>>(hf, W_lin, b_lin, (float*)d_out);
}

// Round 12
// 2783.548 us; speedup vs baseline: 1.4592x; 1.4592x over previous
//
#include <hip/hip_runtime.h>
#include <hip/hip_bf16.h>
#include <cmath>

#define HID 512
#define TSTEPS 784
#define BATCH 256
#define NCLS 10
#define NBLK 256
#define NGRP 16     // groups (16 batch rows each) x 16 col-slices (32 cols)

typedef __bf16 bf16x8 __attribute__((ext_vector_type(8)));
typedef float f32x4 __attribute__((ext_vector_type(4)));
typedef float f32x2 __attribute__((ext_vector_type(2)));
typedef int   i32x4 __attribute__((ext_vector_type(4)));

#define SWS(r) (((unsigned)(r) & 7u) << 4)

// LLC-coherent ops (bypass L1+L2; proven cross-XCD-visible rounds 4/5/9)
#define LDX4_CC(dst, addr) \
    asm volatile("global_load_dwordx4 %0, %1, off sc0 sc1" : "=v"(dst) : "v"(addr) : "memory")
#define STOREDW_CC(addr, val) \
    asm volatile("global_store_dword %0, %1, off sc0 sc1" :: "v"(addr), "v"(val) : "memory")

__device__ __forceinline__ unsigned lddw_cc_wait(const unsigned* a) {
    unsigned d;
    asm volatile("global_load_dword %0, %1, off sc0 sc1\n\ts_waitcnt vmcnt(0)"
                 : "=v"(d) : "v"(a) : "memory");
    return d;
}

// zero h0+h1 (512KB bf16) + flags, transpose x -> xT[784][256]
__global__ void init_all(const float* __restrict__ x, float* __restrict__ xT,
                         uint4* __restrict__ hz, unsigned* __restrict__ flg) {
    int t = blockIdx.x, tid = threadIdx.x;
    xT[t * BATCH + tid] = x[tid * TSTEPS + t];
    int i = t * 256 + tid;
    if (i < (512 << 10) / 16) hz[i] = make_uint4(0u, 0u, 0u, 0u);
    if (i < NGRP * 64) flg[i] = 0u;
}

__device__ __forceinline__ float sigmoid_f(float v) {
    return __fdividef(1.f, 1.f + __expf(-v));
}
__device__ __forceinline__ float tanh_f(float v) {
    float e = __expf(fminf(fmaxf(2.f * v, -30.f), 30.f));
    return __fdividef(e - 1.f, e + 1.f);
}

// Persistent LSTM: 256 blocks = 16 groups(16 batch rows) x 16 col-slices(32 cols).
// W slice (128 gate-rows x 512) in 128KB LDS; c in registers; h via LLC.
// Readiness: per-producer flags; each staging WAVE polls only the 2 producers
// covering its segs (skew absorbed per-producer, no slowest-of-16 barrier).
__global__ __launch_bounds__(512)
void lstm_persist(const float* __restrict__ xT,     // [784][256]
                  const float* __restrict__ W_hh,   // [2048][512] fp32
                  const float* __restrict__ w_in,   // [2048]
                  const float* __restrict__ b_ih,
                  const float* __restrict__ b_hh,
                  __bf16* __restrict__ h0,          // [256][512] bf16
                  __bf16* __restrict__ h1,
                  float* __restrict__ hf,           // [256][512] fp32
                  unsigned* __restrict__ flg)
{
    __shared__ __align__(16) __bf16 wlds[128 * HID];  // 128 KB, XOR-swizzled
    __shared__ __align__(16) __bf16 hlds[16 * HID];   // 16 KB, XOR-swizzled
    __shared__ float gl[4][16][33];                   // gate exchange
    __shared__ float xl[16];

    const int tid  = threadIdx.x;
    const int lane = tid & 63;
    const int w    = tid >> 6;           // wave 0..7
    const int s    = w & 3;              // gate (i,f,g,o)
    const int ch   = w >> 2;             // col half (16 cols each)
    const int bg   = blockIdx.x >> 4;    // group (16)
    const int cs   = blockIdx.x & 15;    // col slice (16)
    const int b0   = bg * 16;
    const int j0   = cs * 32;
    const int rlo  = lane & 15;
    const int khi  = (lane >> 4) * 8;    // elements

    unsigned* flags = flg + bg * 64;     // 256B-separated per-group flag line

    // ---- stage W slice (128 rows x 512) into LDS once (fp32->bf16, swizzled) ----
    {
        int r = tid >> 2;                // local row 0..127
        int q = tid & 3;
        int gs = r >> 5, jj = r & 31;
        const float* src = W_hh + (size_t)(gs * HID + j0 + jj) * HID + q * 128;
        char* wp = (char*)wlds;
        unsigned rowb = (unsigned)r * (HID * 2);
        unsigned sw   = SWS(r);
        #pragma unroll
        for (int cc = 0; cc < 128; cc += 8) {
            float4 va = *(const float4*)(src + cc);
            float4 vb = *(const float4*)(src + cc + 4);
            bf16x8 pk;
            pk[0]=(__bf16)va.x; pk[1]=(__bf16)va.y; pk[2]=(__bf16)va.z; pk[3]=(__bf16)va.w;
            pk[4]=(__bf16)vb.x; pk[5]=(__bf16)vb.y; pk[6]=(__bf16)vb.z; pk[7]=(__bf16)vb.w;
            *(bf16x8*)(wp + ((rowb + (unsigned)(q * 128 + cc) * 2) ^ sw)) = pk;
        }
    }

    // cell mapping (tid<256): row Rc=tid>>4 (0..15), cols c2,c2+1 (of 32)
    const int Rc = tid >> 4;
    const int c2 = (tid & 15) * 2;
    float win_r[4][2], bias_r[4][2];
    #pragma unroll
    for (int g = 0; g < 4; ++g)
        #pragma unroll
        for (int ii = 0; ii < 2; ++ii) {
            int idx = g * HID + j0 + c2 + ii;
            win_r[g][ii]  = w_in[idx];
            bias_r[g][ii] = b_ih[idx] + b_hh[idx];
        }
    float creg[2] = {0.f, 0.f};

    // staging mapping: row rS (0..15), segment seg (0..31) of 16 bf16 cols (32B)
    const int rS  = tid & 15;
    const int seg = tid >> 4;
    const unsigned rowbS = (unsigned)rS * (HID * 2);
    const unsigned swS   = SWS(rS);
    const unsigned* myflag = flags + (seg >> 1);   // producer of my 16 cols

    // B-fragment base: local W row rB = s*32 + ch*16 + rlo
    const unsigned rBb = (unsigned)(s * 32 + ch * 16 + rlo) * (HID * 2);
    const unsigned swB = SWS(rlo);
    const char* wbp = (const char*)wlds;
    const char* hbp = (const char*)hlds;
    char* hwp = (char*)hlds;

    __syncthreads();

    for (int t = 0; t < TSTEPS; ++t) {
        const __bf16* hprev = (t & 1) ? h1 : h0;
        __bf16* hnext       = (t & 1) ? h0 : h1;

        // ---- stage: x early; per-wave poll of own 2 producers; then load ----
        if (tid < 16) xl[tid] = xT[t * BATCH + b0 + tid];
        {
            while (lddw_cc_wait(myflag) < (unsigned)t) __builtin_amdgcn_s_sleep(1);
            const __bf16* gsrc = hprev + (size_t)(b0 + rS) * HID + seg * 16;
            i32x4 v0, v1;
            LDX4_CC(v0, gsrc);
            LDX4_CC(v1, gsrc + 8);
            asm volatile("s_waitcnt vmcnt(0)" ::: "memory");
            __builtin_amdgcn_sched_barrier(0);
            unsigned base = rowbS + (unsigned)seg * 32u;
            *(i32x4*)(hwp + ((base +  0u) ^ swS)) = v0;
            *(i32x4*)(hwp + ((base + 16u) ^ swS)) = v1;
        }
        __syncthreads();   // A: hlds + xl ready

        // ---- gates tile: 16 rows x 16 cols for gate s, col-half ch ----
        f32x4 acc_e = {0.f,0.f,0.f,0.f}, acc_o = {0.f,0.f,0.f,0.f};
        #pragma unroll
        for (int ks = 0; ks < 16; ks += 2) {
            unsigned colb0 = (unsigned)(khi * 2 + ks * 64);
            unsigned colb1 = colb0 + 64u;
            bf16x8 a0 = *(const bf16x8*)(hbp + (((unsigned)rlo * 1024u + colb0) ^ SWS(rlo)));
            bf16x8 b0f = *(const bf16x8*)(wbp + ((rBb + colb0) ^ swB));
            bf16x8 a1 = *(const bf16x8*)(hbp + (((unsigned)rlo * 1024u + colb1) ^ SWS(rlo)));
            bf16x8 b1f = *(const bf16x8*)(wbp + ((rBb + colb1) ^ swB));
            acc_e = __builtin_amdgcn_mfma_f32_16x16x32_bf16(a0, b0f, acc_e, 0, 0, 0);
            acc_o = __builtin_amdgcn_mfma_f32_16x16x32_bf16(a1, b1f, acc_o, 0, 0, 0);
        }
        f32x4 acc0 = acc_e + acc_o;
        #pragma unroll
        for (int rr = 0; rr < 4; ++rr) {
            int rowl = (lane >> 4) * 4 + rr;   // D: col=lane&15, row=(lane>>4)*4+reg
            gl[s][rowl][ch * 16 + rlo] = acc0[rr];
        }
        __syncthreads();   // A2: gl ready

        // ---- cell update (tid<256: 2 cols), h store to LLC ----
        if (tid < 256) {
            float xv = xl[Rc];
            float hn2[2];
            #pragma unroll
            for (int ii = 0; ii < 2; ++ii) {
                int ccx = c2 + ii;
                float gi = gl[0][Rc][ccx] + xv * win_r[0][ii] + bias_r[0][ii];
                float gf = gl[1][Rc][ccx] + xv * win_r[1][ii] + bias_r[1][ii];
                float gg = gl[2][Rc][ccx] + xv * win_r[2][ii] + bias_r[2][ii];
                float go = gl[3][Rc][ccx] + xv * win_r[3][ii] + bias_r[3][ii];
                float cn = sigmoid_f(gf) * creg[ii] + sigmoid_f(gi) * tanh_f(gg);
                creg[ii] = cn;
                hn2[ii]  = sigmoid_f(go) * tanh_f(cn);
            }
            if (t == TSTEPS - 1) {
                *(f32x2*)(hf + (size_t)(b0 + Rc) * HID + j0 + c2) = (f32x2){hn2[0], hn2[1]};
            } else {
                union { __bf16 b[2]; int i; } u;
                u.b[0] = (__bf16)hn2[0]; u.b[1] = (__bf16)hn2[1];
                __bf16* dst = hnext + (size_t)(b0 + Rc) * HID + j0 + c2;
                STOREDW_CC(dst, u.i);
            }
        }
        if (t == TSTEPS - 1) break;

        // ---- drain + publish (flag = t+1) ----
        asm volatile("s_waitcnt vmcnt(0)" ::: "memory");   // own h stores at LLC
        __syncthreads();                                   // B: whole block drained
        if (tid == 0) STOREDW_CC(flags + cs, (int)(t + 1));
    }
}

// out[b][j] = h_T[b] . W_lin[j] + b_lin[j]
__global__ void head(const float* __restrict__ hfp, const float* __restrict__ Wl,
                     const float* __restrict__ bl_, float* __restrict__ out)
{
    __shared__ float hr[HID];
    int b = blockIdx.x;
    for (int k = threadIdx.x; k < HID; k += blockDim.x) hr[k] = hfp[b * HID + k];
    __syncthreads();
    int j = threadIdx.x;
    if (j < NCLS) {
        float acc = bl_[j];
        for (int k = 0; k < HID; ++k) acc += hr[k] * Wl[j * HID + k];
        out[b * NCLS + j] = acc;
    }
}

extern "C" void kernel_launch(void* const* d_in, const int* in_sizes, int n_in,
                              void* d_out, int out_size, void* d_ws, size_t ws_size,
                              hipStream_t stream) {
    const float* inputs = (const float*)d_in[0];
    const float* W_ih   = (const float*)d_in[1];
    const float* W_hh   = (const float*)d_in[2];
    const float* b_ih   = (const float*)d_in[3];
    const float* b_hh   = (const float*)d_in[4];
    const float* W_lin  = (const float*)d_in[5];
    const float* b_lin  = (const float*)d_in[6];

    // ws: h0 256K | h1 256K | hf 512K | xT 784K | flags 4K
    const size_t OFS_H1  = 256u << 10;
    const size_t OFS_HF  = 512u << 10;
    const size_t OFS_XT  = 1024u << 10;
    const size_t OFS_FLG = OFS_XT + (size_t)TSTEPS * BATCH * 4;   // 128B-aligned
    const size_t NEEDED  = OFS_FLG + NGRP * 64 * 4;
    if (ws_size < NEEDED) return;

    char* ws = (char*)d_ws;
    __bf16* h0 = (__bf16*)ws;
    __bf16* h1 = (__bf16*)(ws + OFS_H1);
    float*  hf = (float*)(ws + OFS_HF);
    float*  xT = (float*)(ws + OFS_XT);
    unsigned* flg = (unsigned*)(ws + OFS_FLG);

    init_all<<<TSTEPS, BATCH, 0, stream>>>(inputs, xT, (uint4*)h0, flg);

    lstm_persist<<<NBLK, 512, 0, stream>>>(xT, W_hh, W_ih, b_ih, b_hh,
                                           h0, h1, hf, flg);

    head<<<BATCH, 64, 0, stream>>>(hf, W_lin, b_lin, (float*)d_out);
}